// Round 10
// baseline (390.498 us; speedup 1.0000x reference)
//
#include <hip/hip_runtime.h>
#include <stdint.h>

#define SEQ      1024
#define NT       128
#define NBATCH   256
#define MID      512          // fwd -> alpha_512 ; bwd -> beta_512
#define WS_STRIDE 132         // 128 floats + kSum

typedef float v2f __attribute__((ext_vector_type(2)));

// 64 NAMED v2f weight registers (no arrays -> no scratch indexing), each
// pinned by an asm barrier after init so the compiler can neither spill-
// rematerialize (reload+exp) nor sink the init into the loop.
#define RALL(X) \
  X(0) X(1) X(2) X(3) X(4) X(5) X(6) X(7) X(8) X(9) X(10) X(11) X(12) X(13) X(14) X(15) \
  X(16) X(17) X(18) X(19) X(20) X(21) X(22) X(23) X(24) X(25) X(26) X(27) X(28) X(29) X(30) X(31) \
  X(32) X(33) X(34) X(35) X(36) X(37) X(38) X(39) X(40) X(41) X(42) X(43) X(44) X(45) X(46) X(47) \
  X(48) X(49) X(50) X(51) X(52) X(53) X(54) X(55) X(56) X(57) X(58) X(59) X(60) X(61) X(62) X(63)

#define DECLW(k) v2f W##k;
#define INITW(k) { \
    W##k.x = __expf(wbase[(2 * (k)    ) * wstr]); \
    W##k.y = __expf(wbase[(2 * (k) + 1) * wstr]); }
#define PINW(k)  asm volatile("" : "+v"(W##k));

#define MACC(c, ka, kb, kc, kd) { \
    float4 ga = *(const float4*)(gp + 8 * (c)); \
    float4 gb = *(const float4*)(gp + 8 * (c) + 4); \
    v2f a0 = {ga.x, ga.y}, a1 = {ga.z, ga.w}; \
    v2f b0 = {gb.x, gb.y}, b1 = {gb.z, gb.w}; \
    s0 = __builtin_elementwise_fma(W##ka, a0, s0); \
    s1 = __builtin_elementwise_fma(W##kb, a1, s1); \
    s2 = __builtin_elementwise_fma(W##kc, b0, s2); \
    s3 = __builtin_elementwise_fma(W##kd, b1, s3); }

#define MATVEC128(S_) { \
    v2f s0 = {0,0}, s1 = {0,0}, s2 = {0,0}, s3 = {0,0}; \
    MACC(0,0,1,2,3)     MACC(1,4,5,6,7)     MACC(2,8,9,10,11)   MACC(3,12,13,14,15) \
    MACC(4,16,17,18,19) MACC(5,20,21,22,23) MACC(6,24,25,26,27) MACC(7,28,29,30,31) \
    MACC(8,32,33,34,35) MACC(9,36,37,38,39) MACC(10,40,41,42,43) MACC(11,44,45,46,47) \
    MACC(12,48,49,50,51) MACC(13,52,53,54,55) MACC(14,56,57,58,59) MACC(15,60,61,62,63) \
    S_ = ((s0.x + s0.y) + (s1.x + s1.y)) + ((s2.x + s2.y) + (s3.x + s3.y)); }

// blocks [0,256):   one block per batch; waves 0-1 = forward chain (steps 1..512,
//                   thread = output tag), waves 2-3 = backward chain (1023..513).
// blocks [256,320): score gathers (4 batches each)
__global__ __launch_bounds__(256, 1)
__attribute__((amdgpu_waves_per_eu(1, 1)))
void crf_chains(
    const float* __restrict__ emissions,   // [B, SEQ, NT]
    const float* __restrict__ transitions, // [NT, NT]
    const int*   __restrict__ tags,        // [B, SEQ]
    const float* __restrict__ mask,        // [B, SEQ]
    float* __restrict__ out,               // [1]
    float* __restrict__ ws)                // [2*256*132]
{
    const int blk = blockIdx.x;
    const int tid = threadIdx.x;

    if (blk >= NBATCH) {
        // ---------------- score blocks ----------------
        int b    = (blk - NBATCH) * 4 + (tid >> 6);
        int lane = tid & 63;
        const float* emb = emissions + (size_t)b * SEQ * NT;
        const int*   tgb = tags + (size_t)b * SEQ;
        const float* mkb = mask + (size_t)b * SEQ;
        float sc = 0.f;
        for (int t = lane; t < SEQ; t += 64) {
            int   tg = tgb[t];
            float mt = mkb[t];
            sc += emb[t * NT + tg] * mt;
            if (t >= 1) sc += transitions[tgb[t - 1] * NT + tg] * mt;
        }
#pragma unroll
        for (int o = 32; o > 0; o >>= 1) sc += __shfl_down(sc, o, 64);
        if (lane == 0) atomicAdd(out, -sc * (1.0f / NBATCH));
        return;
    }

    // ---------------- chain block for batch b ----------------
    __shared__ __align__(16) float bufF[2][NT];
    __shared__ __align__(16) float bufB[2][NT];

    const int b    = blk;
    const int half = tid >> 7;    // 0 = forward, 1 = backward (wave-aligned)
    const int jt   = tid & 127;   // owned tag

    const float* emb = emissions + (size_t)b * SEQ * NT;
    const float* mkb = mask + (size_t)b * SEQ;

    // fwd: column jt (stride NT); bwd: row jt (stride 1)
    const float* wbase = half ? (transitions + (size_t)jt * NT) : (transitions + jt);
    const int    wstr  = half ? 1 : NT;

    RALL(DECLW)
    RALL(INITW)
    RALL(PINW)

    if (half == 0) bufF[0][jt] = __expf(emb[jt]);
    else           bufB[0][jt] = __expf(emb[(size_t)(SEQ - 1) * NT + jt]);
    __syncthreads();

    int   kSum = 0, p = 0;
    float beta = 1.0f;

    // prefetch depth 2: E = emission this thread's step needs, M = step mask
    float E0, E1, M0, M1;
    if (half == 0) {   // fwd it-th step: t = 1+it, needs E[t], mkb[t]
        E0 = emb[1 * NT + jt];  E1 = emb[2 * NT + jt];
        M0 = mkb[1];            M1 = mkb[2];
    } else {           // bwd it-th step: t = 1023-it, needs E[t-1], mkb[t]
        E0 = emb[(size_t)(SEQ - 2) * NT + jt];
        E1 = emb[(size_t)(SEQ - 3) * NT + jt];
        M0 = mkb[SEQ - 1];      M1 = mkb[SEQ - 2];
    }

    for (int it = 0; it < MID; ++it) {
        float En, Mn;
        if (half == 0) { En = emb[(size_t)(3 + it) * NT + jt];    Mn = mkb[3 + it]; }
        else           { En = emb[(size_t)(1020 - it) * NT + jt]; Mn = mkb[1021 - it]; }

        if (half == 0) {
            // alpha_t = (alpha^T expT) .* expE_t, exact 2^-k rescale
            if (M0 != 0.0f) {
                const float* gp = bufF[p];
                float s;
                MATVEC128(s);
                float c0 = gp[0];
                int   k  = (int)(__float_as_uint(c0) >> 23) - 127;
                float rc = __uint_as_float((uint32_t)(127 - k) << 23);
                kSum += k;
                bufF[p ^ 1][jt] = s * rc * __expf(E0);
                p ^= 1;
            }
        } else if (it < MID - 1) {
            // beta_{t-1} = expT (expE_t .* beta_t); buf holds w = expE .* beta
            const float* gp = bufB[p];
            float s;
            MATVEC128(s);
            float c0 = gp[0];
            int   k  = (int)(__float_as_uint(c0) >> 23) - 127;
            float rc = __uint_as_float((uint32_t)(127 - k) << 23);
            kSum += k;
            float bn = (M0 != 0.0f) ? s * rc : beta * rc;
            beta = bn;
            bufB[p ^ 1][jt] = bn * __expf(E0);
            p ^= 1;
        }
        E0 = E1; E1 = En; M0 = M1; M1 = Mn;
        __syncthreads();
    }

    float* wsb = ws + (size_t)(half * NBATCH + b) * WS_STRIDE;
    if (half == 0) {
        wsb[jt] = bufF[p][jt];            // alpha_512 (pow2-scaled)
        if (jt == 0) wsb[128] = (float)kSum;
    } else {
        wsb[jt] = beta;                   // beta_512 (pow2-scaled)
        if (jt == 0) wsb[128] = (float)kSum;
    }
}

// Z = sum_i alpha_MID[i] * beta_MID[i] * 2^(kF+kB)
__global__ __launch_bounds__(64) void crf_combine(
    const float* __restrict__ ws, float* __restrict__ out)
{
    int b    = blockIdx.x;
    int lane = threadIdx.x;
    const float* af = ws + (size_t)b * WS_STRIDE;
    const float* bf = ws + (size_t)(NBATCH + b) * WS_STRIDE;
    float d = af[lane] * bf[lane] + af[lane + 64] * bf[lane + 64];
#pragma unroll
    for (int o = 32; o > 0; o >>= 1) d += __shfl_down(d, o, 64);
    if (lane == 0) {
        float logZ = __logf(d) + (af[128] + bf[128]) * 0.69314718055994531f;
        atomicAdd(out, logZ * (1.0f / NBATCH));
    }
}

extern "C" void kernel_launch(void* const* d_in, const int* in_sizes, int n_in,
                              void* d_out, int out_size, void* d_ws, size_t ws_size,
                              hipStream_t stream) {
    const float* emissions   = (const float*)d_in[0];
    const float* transitions = (const float*)d_in[1];
    const int*   tags        = (const int*)d_in[2];
    const float* mask        = (const float*)d_in[3];
    float*       out         = (float*)d_out;
    float*       ws          = (float*)d_ws;

    hipMemsetAsync(out, 0, sizeof(float), stream);
    crf_chains<<<NBATCH + 64, 256, 0, stream>>>(
        emissions, transitions, tags, mask, out, ws);
    crf_combine<<<NBATCH, 64, 0, stream>>>(ws, out);
}

// Round 11
// 332.795 us; speedup vs baseline: 1.1734x; 1.1734x over previous
//
#include <hip/hip_runtime.h>
#include <stdint.h>

#define SEQ      1024
#define NT       128
#define NBATCH   256
#define MID      512          // fwd -> alpha_512 ; bwd -> beta_512
#define WS_STRIDE 132         // 128 floats + kSum

// bf16 pair dot: a += su.{lo,hi} * wu.{lo,hi}  (f32 accumulate)
#if defined(__has_builtin)
#if __has_builtin(__builtin_amdgcn_fdot2_f32_bf16)
#define HAVE_BF16_DOT2 1
#endif
#endif

#ifdef HAVE_BF16_DOT2
typedef __bf16 v2bf __attribute__((ext_vector_type(2)));
#define DOT2ACC(a, su, wu) \
    a = __builtin_amdgcn_fdot2_f32_bf16(__builtin_bit_cast(v2bf, (su)), \
                                        __builtin_bit_cast(v2bf, (wu)), a, false)
#else
#define DOT2ACC(a, su, wu) { \
    a = fmaf(__uint_as_float((wu) << 16),          __uint_as_float((su) << 16),          a); \
    a = fmaf(__uint_as_float((wu) & 0xffff0000u),  __uint_as_float((su) & 0xffff0000u),  a); }
#endif

// 64 NAMED u32 weight registers (bf16 pairs) -> 64 VGPRs, fits the allocator's
// demonstrated budget; pinned so they can't be rematerialized (load+exp+cvt).
#define RALL(X) \
  X(0) X(1) X(2) X(3) X(4) X(5) X(6) X(7) X(8) X(9) X(10) X(11) X(12) X(13) X(14) X(15) \
  X(16) X(17) X(18) X(19) X(20) X(21) X(22) X(23) X(24) X(25) X(26) X(27) X(28) X(29) X(30) X(31) \
  X(32) X(33) X(34) X(35) X(36) X(37) X(38) X(39) X(40) X(41) X(42) X(43) X(44) X(45) X(46) X(47) \
  X(48) X(49) X(50) X(51) X(52) X(53) X(54) X(55) X(56) X(57) X(58) X(59) X(60) X(61) X(62) X(63)

#define DECLW(k) uint32_t W##k;
#define INITW(k) { \
    float f0_ = __expf(wbase[(2 * (k)    ) * wstr]); \
    float f1_ = __expf(wbase[(2 * (k) + 1) * wstr]); \
    asm("v_cvt_pk_bf16_f32 %0, %1, %2" : "=v"(W##k) : "v"(f0_), "v"(f1_)); }
#define PINW(k)  asm volatile("" : "+v"(W##k));

#define MACC(c, k0, k1, k2, k3) { \
    uint4 u_ = *(const uint4*)(gp + 4 * (c)); \
    DOT2ACC(a0, u_.x, W##k0); \
    DOT2ACC(a1, u_.y, W##k1); \
    DOT2ACC(a2, u_.z, W##k2); \
    DOT2ACC(a3, u_.w, W##k3); }

#define MATVEC128(S_) { \
    float a0 = 0.f, a1 = 0.f, a2 = 0.f, a3 = 0.f; \
    MACC(0,0,1,2,3)      MACC(1,4,5,6,7)      MACC(2,8,9,10,11)    MACC(3,12,13,14,15) \
    MACC(4,16,17,18,19)  MACC(5,20,21,22,23)  MACC(6,24,25,26,27)  MACC(7,28,29,30,31) \
    MACC(8,32,33,34,35)  MACC(9,36,37,38,39)  MACC(10,40,41,42,43) MACC(11,44,45,46,47) \
    MACC(12,48,49,50,51) MACC(13,52,53,54,55) MACC(14,56,57,58,59) MACC(15,60,61,62,63) \
    S_ = (a0 + a1) + (a2 + a3); }

// blocks [0,256):   one block per batch; waves 0-1 = forward chain (steps 1..512,
//                   thread = output tag), waves 2-3 = backward chain (1023..513).
// blocks [256,320): score gathers (4 batches each)
__global__ __launch_bounds__(256) void crf_chains(
    const float* __restrict__ emissions,   // [B, SEQ, NT]
    const float* __restrict__ transitions, // [NT, NT]
    const int*   __restrict__ tags,        // [B, SEQ]
    const float* __restrict__ mask,        // [B, SEQ]
    float* __restrict__ out,               // [1]
    float* __restrict__ ws)                // [2*256*132]
{
    const int blk = blockIdx.x;
    const int tid = threadIdx.x;

    if (blk >= NBATCH) {
        // ---------------- score blocks ----------------
        int b    = (blk - NBATCH) * 4 + (tid >> 6);
        int lane = tid & 63;
        const float* emb = emissions + (size_t)b * SEQ * NT;
        const int*   tgb = tags + (size_t)b * SEQ;
        const float* mkb = mask + (size_t)b * SEQ;
        float sc = 0.f;
        for (int t = lane; t < SEQ; t += 64) {
            int   tg = tgb[t];
            float mt = mkb[t];
            sc += emb[t * NT + tg] * mt;
            if (t >= 1) sc += transitions[tgb[t - 1] * NT + tg] * mt;
        }
#pragma unroll
        for (int o = 32; o > 0; o >>= 1) sc += __shfl_down(sc, o, 64);
        if (lane == 0) atomicAdd(out, -sc * (1.0f / NBATCH));
        return;
    }

    // ---------------- chain block for batch b ----------------
    // state = 64 u32 of bf16 pairs (tag 2q lo, 2q+1 hi), double-buffered
    __shared__ __align__(16) uint32_t bufF[2][NT / 2];
    __shared__ __align__(16) uint32_t bufB[2][NT / 2];

    const int b    = blk;
    const int half = tid >> 7;    // 0 = forward, 1 = backward (wave-aligned)
    const int jt   = tid & 127;   // owned tag

    const float* emb = emissions + (size_t)b * SEQ * NT;
    const float* mkb = mask + (size_t)b * SEQ;

    // fwd: column jt (stride NT); bwd: row jt (stride 1)
    const float* wbase = half ? (transitions + (size_t)jt * NT) : (transitions + jt);
    const int    wstr  = half ? 1 : NT;

    RALL(DECLW)
    RALL(INITW)
    RALL(PINW)

    // init states (bf16, rounded)
    {
        float g0 = half ? __expf(emb[(size_t)(SEQ - 1) * NT + jt]) : __expf(emb[jt]);
        uint32_t pk;
        asm("v_cvt_pk_bf16_f32 %0, %1, %2" : "=v"(pk) : "v"(g0), "v"(g0));
        unsigned short* dst = (unsigned short*)(half ? bufB[0] : bufF[0]);
        dst[jt] = (unsigned short)(pk & 0xffffu);
    }
    __syncthreads();

    int   kSum = 0, p = 0;
    float beta = 1.0f;

    // prefetch depth 2: E = emission this thread's step needs, M = step mask
    float E0, E1, M0, M1;
    if (half == 0) {   // fwd it-th step: t = 1+it, needs E[t], mkb[t]
        E0 = emb[1 * NT + jt];  E1 = emb[2 * NT + jt];
        M0 = mkb[1];            M1 = mkb[2];
    } else {           // bwd it-th step: t = 1023-it, needs E[t-1], mkb[t]
        E0 = emb[(size_t)(SEQ - 2) * NT + jt];
        E1 = emb[(size_t)(SEQ - 3) * NT + jt];
        M0 = mkb[SEQ - 1];      M1 = mkb[SEQ - 2];
    }

    for (int it = 0; it < MID; ++it) {
        float En, Mn;
        if (half == 0) { En = emb[(size_t)(3 + it) * NT + jt];    Mn = mkb[3 + it]; }
        else           { En = emb[(size_t)(1020 - it) * NT + jt]; Mn = mkb[1021 - it]; }

        if (half == 0) {
            // alpha_t = (alpha^T expT) .* expE_t, exact 2^-k rescale (anchor tag0)
            if (M0 != 0.0f) {
                const uint32_t* gp = bufF[p];
                uint32_t h01 = gp[0];
                float s;
                MATVEC128(s);
                int   e  = (int)((h01 >> 7) & 0xff);         // bf16 exp of tag0
                float rc = __uint_as_float((uint32_t)(254 - e) << 23);  // 2^-(e-127)
                kSum += e - 127;
                float g = s * rc * __expf(E0);
                uint32_t pk;
                asm("v_cvt_pk_bf16_f32 %0, %1, %2" : "=v"(pk) : "v"(g), "v"(g));
                ((unsigned short*)bufF[p ^ 1])[jt] = (unsigned short)(pk & 0xffffu);
                p ^= 1;
            }
        } else if (it < MID - 1) {
            // beta_{t-1} = expT (expE_t .* beta_t); buf holds w = expE .* beta
            const uint32_t* gp = bufB[p];
            uint32_t h01 = gp[0];
            float s;
            MATVEC128(s);
            int   e  = (int)((h01 >> 7) & 0xff);
            float rc = __uint_as_float((uint32_t)(254 - e) << 23);
            kSum += e - 127;
            float bn = (M0 != 0.0f) ? s * rc : beta * rc;
            beta = bn;
            float g = bn * __expf(E0);
            uint32_t pk;
            asm("v_cvt_pk_bf16_f32 %0, %1, %2" : "=v"(pk) : "v"(g), "v"(g));
            ((unsigned short*)bufB[p ^ 1])[jt] = (unsigned short)(pk & 0xffffu);
            p ^= 1;
        }
        E0 = E1; E1 = En; M0 = M1; M1 = Mn;
        __syncthreads();
    }

    float* wsb = ws + (size_t)(half * NBATCH + b) * WS_STRIDE;
    if (half == 0) {
        uint32_t u = bufF[p][jt >> 1];
        float v = (jt & 1) ? __uint_as_float(u & 0xffff0000u)
                           : __uint_as_float(u << 16);
        wsb[jt] = v;                      // alpha_512 (pow2-scaled)
        if (jt == 0) wsb[128] = (float)kSum;
    } else {
        wsb[jt] = beta;                   // beta_512 (pow2-scaled)
        if (jt == 0) wsb[128] = (float)kSum;
    }
}

// Z = sum_i alpha_MID[i] * beta_MID[i] * 2^(kF+kB)
__global__ __launch_bounds__(64) void crf_combine(
    const float* __restrict__ ws, float* __restrict__ out)
{
    int b    = blockIdx.x;
    int lane = threadIdx.x;
    const float* af = ws + (size_t)b * WS_STRIDE;
    const float* bf = ws + (size_t)(NBATCH + b) * WS_STRIDE;
    float d = af[lane] * bf[lane] + af[lane + 64] * bf[lane + 64];
#pragma unroll
    for (int o = 32; o > 0; o >>= 1) d += __shfl_down(d, o, 64);
    if (lane == 0) {
        float logZ = __logf(d) + (af[128] + bf[128]) * 0.69314718055994531f;
        atomicAdd(out, logZ * (1.0f / NBATCH));
    }
}

extern "C" void kernel_launch(void* const* d_in, const int* in_sizes, int n_in,
                              void* d_out, int out_size, void* d_ws, size_t ws_size,
                              hipStream_t stream) {
    const float* emissions   = (const float*)d_in[0];
    const float* transitions = (const float*)d_in[1];
    const int*   tags        = (const int*)d_in[2];
    const float* mask        = (const float*)d_in[3];
    float*       out         = (float*)d_out;
    float*       ws          = (float*)d_ws;

    hipMemsetAsync(out, 0, sizeof(float), stream);
    crf_chains<<<NBATCH + 64, 256, 0, stream>>>(
        emissions, transitions, tags, mask, out, ws);
    crf_combine<<<NBATCH, 64, 0, stream>>>(ws, out);
}